// Round 1
// baseline (65090.277 us; speedup 1.0000x reference)
//
#include <hip/hip_runtime.h>

#define Bb 32
#define Ll 512
#define Dd 1024
#define Hh 256
#define Ee 64

__device__ __forceinline__ float sigmoidf_(float x) { return 1.f / (1.f + __expf(-x)); }
__device__ __forceinline__ float tanhf_(float x) { return 1.f - 2.f / (__expf(2.f * x) + 1.f); }

// ---------------------------------------------------------------------------
// xg GEMM: out[dir][m][n] = sum_k A[m][k] * W[dir][n][k] + bias[dir][n]
// m = t*B + b (16384 rows), n in [0,1024). XL: A is x with (B,L,D) layout.
// grid: (32, 256) -> blockIdx.x = dir*16 + ntile, blockIdx.y = mtile; 256 thr
// ---------------------------------------------------------------------------
template <int DK, bool XL>
__global__ __launch_bounds__(256) void xg_gemm(const float* __restrict__ A,
                                               const float* __restrict__ W,
                                               const float* __restrict__ bias,
                                               float* __restrict__ xg) {
  const int dir = blockIdx.x >> 4;
  const int n0 = (blockIdx.x & 15) * 64;
  const int m0 = blockIdx.y * 64;
  const float* Wd = W + (size_t)dir * (4 * Hh * DK);
  const float* bd = bias + dir * (4 * Hh);
  float* out = xg + (size_t)dir * ((size_t)Ll * Bb * 4 * Hh);

  __shared__ __align__(16) float As[16][72];
  __shared__ __align__(16) float Bs[16][72];

  const int tid = threadIdx.x;
  const int tm = (tid >> 4) * 4;
  const int tn4 = (tid & 15) * 4;

  float acc[4][4] = {};

  for (int k0 = 0; k0 < DK; k0 += 16) {
    // load A tile (64 rows x 16 k) and B tile (64 n-rows x 16 k)
    const int r = tid >> 2;         // 0..63
    const int c = (tid & 3) * 4;    // 0,4,8,12
    size_t aoff;
    const int m = m0 + r;
    if (XL) {
      const int t = m >> 5, b = m & 31;
      aoff = ((size_t)(b * Ll + t)) * DK + (k0 + c);
    } else {
      aoff = (size_t)m * DK + (k0 + c);
    }
    float4 av = *(const float4*)(A + aoff);
    As[c + 0][r] = av.x; As[c + 1][r] = av.y; As[c + 2][r] = av.z; As[c + 3][r] = av.w;
    float4 wv = *(const float4*)(Wd + (size_t)(n0 + r) * DK + (k0 + c));
    Bs[c + 0][r] = wv.x; Bs[c + 1][r] = wv.y; Bs[c + 2][r] = wv.z; Bs[c + 3][r] = wv.w;
    __syncthreads();

#pragma unroll
    for (int kk = 0; kk < 16; kk++) {
      float4 a4 = *(const float4*)&As[kk][tm];
      float4 b4 = *(const float4*)&Bs[kk][tn4];
      acc[0][0] += a4.x * b4.x; acc[0][1] += a4.x * b4.y; acc[0][2] += a4.x * b4.z; acc[0][3] += a4.x * b4.w;
      acc[1][0] += a4.y * b4.x; acc[1][1] += a4.y * b4.y; acc[1][2] += a4.y * b4.z; acc[1][3] += a4.y * b4.w;
      acc[2][0] += a4.z * b4.x; acc[2][1] += a4.z * b4.y; acc[2][2] += a4.z * b4.z; acc[2][3] += a4.z * b4.w;
      acc[3][0] += a4.w * b4.x; acc[3][1] += a4.w * b4.y; acc[3][2] += a4.w * b4.z; acc[3][3] += a4.w * b4.w;
    }
    __syncthreads();
  }

  const float4 bv = *(const float4*)&bd[n0 + tn4];
#pragma unroll
  for (int i = 0; i < 4; i++) {
    float4 v;
    v.x = acc[i][0] + bv.x; v.y = acc[i][1] + bv.y; v.z = acc[i][2] + bv.z; v.w = acc[i][3] + bv.w;
    *(float4*)&out[(size_t)(m0 + tm + i) * 1024 + n0 + tn4] = v;
  }
}

// ---------------------------------------------------------------------------
// One LSTM time step, both directions.
// grid 64 = dir(2) x bh(2) x jslice(16); block 256 = bloc(16) x jloc(16)
// whh: (2, 1024, 256) for this layer. xg: (2, L*B, 1024) incl bias.
// hstate/cstate: (2, 32, 256). out: (L*B, 512), masked write.
// ---------------------------------------------------------------------------
__global__ __launch_bounds__(256) void lstm_step(const float* __restrict__ whh,
                                                 const float* __restrict__ xg,
                                                 const int* __restrict__ lens,
                                                 float* __restrict__ hstate,
                                                 float* __restrict__ cstate,
                                                 float* __restrict__ out,
                                                 int t) {
  const int dir = blockIdx.x >> 5;
  const int bh = (blockIdx.x >> 4) & 1;
  const int js = blockIdx.x & 15;
  const int tid = threadIdx.x;
  const int jloc = tid & 15;
  const int bloc = tid >> 4;
  const int ju = js * 16 + jloc;
  const int bglob = bh * 16 + bloc;

  __shared__ __align__(16) float h_lds[16][256];
  // stage previous h for our 16 batches
  for (int idx = tid; idx < 16 * 256; idx += 256) {
    const int bi = idx >> 8, k = idx & 255;
    h_lds[bi][k] = (t == 0) ? 0.f : hstate[dir * (Bb * Hh) + (bh * 16 + bi) * Hh + k];
  }
  __syncthreads();

  const int len_b = lens[bglob];
  const int tt = dir ? ((t < len_b) ? (len_b - 1 - t) : t) : t;

  const float* xgrow = xg + ((size_t)dir * Ll * Bb + (size_t)tt * Bb + bglob) * 1024;
  float acc0 = xgrow[0 * 256 + ju];
  float acc1 = xgrow[1 * 256 + ju];
  float acc2 = xgrow[2 * 256 + ju];
  float acc3 = xgrow[3 * 256 + ju];

  const float* wbase = whh + (size_t)dir * (1024 * 256);
  const float* w0 = wbase + (size_t)(0 * 256 + ju) * 256;
  const float* w1 = wbase + (size_t)(1 * 256 + ju) * 256;
  const float* w2 = wbase + (size_t)(2 * 256 + ju) * 256;
  const float* w3 = wbase + (size_t)(3 * 256 + ju) * 256;

#pragma unroll 4
  for (int k4 = 0; k4 < 256; k4 += 4) {
    const float4 h4 = *(const float4*)&h_lds[bloc][k4];
    float4 a = *(const float4*)(w0 + k4);
    acc0 += h4.x * a.x + h4.y * a.y + h4.z * a.z + h4.w * a.w;
    float4 b = *(const float4*)(w1 + k4);
    acc1 += h4.x * b.x + h4.y * b.y + h4.z * b.z + h4.w * b.w;
    float4 c = *(const float4*)(w2 + k4);
    acc2 += h4.x * c.x + h4.y * c.y + h4.z * c.z + h4.w * c.w;
    float4 d = *(const float4*)(w3 + k4);
    acc3 += h4.x * d.x + h4.y * d.y + h4.z * d.z + h4.w * d.w;
  }

  const float cprev = (t == 0) ? 0.f : cstate[dir * (Bb * Hh) + bglob * Hh + ju];
  const float ig = sigmoidf_(acc0);
  const float fg = sigmoidf_(acc1);
  const float gg = tanhf_(acc2);
  const float og = sigmoidf_(acc3);
  const float cnew = fg * cprev + ig * gg;
  const float hnew = og * tanhf_(cnew);

  cstate[dir * (Bb * Hh) + bglob * Hh + ju] = cnew;
  hstate[dir * (Bb * Hh) + bglob * Hh + ju] = hnew;
  out[((size_t)tt * Bb + bglob) * 512 + dir * 256 + ju] = (tt < len_b) ? hnew : 0.f;
}

// ---------------------------------------------------------------------------
// emit[b][t][e] = softmax_e(out_row(t,b) . fc_w[e] + fc_b[e])
// grid 16384 (= t*B + b), block 64 (one wave, thread = e)
// ---------------------------------------------------------------------------
__global__ __launch_bounds__(64) void emit_kernel(const float* __restrict__ out,
                                                  const float* __restrict__ fcw,
                                                  const float* __restrict__ fcb,
                                                  float* __restrict__ emit) {
  __shared__ __align__(16) float row[512];
  const int e = threadIdx.x;
  const int m = blockIdx.x;           // t*B + b
  const int b = m & 31, t = m >> 5;
  for (int i = e; i < 512; i += 64) row[i] = out[(size_t)m * 512 + i];
  __syncthreads();

  float acc = fcb[e];
  const float* we = fcw + (size_t)e * 512;
#pragma unroll 4
  for (int k = 0; k < 512; k += 4) {
    const float4 r4 = *(const float4*)&row[k];
    const float4 w4 = *(const float4*)(we + k);
    acc += r4.x * w4.x + r4.y * w4.y + r4.z * w4.z + r4.w * w4.w;
  }
  float mx = acc;
  for (int off = 32; off; off >>= 1) mx = fmaxf(mx, __shfl_xor(mx, off));
  const float ex = __expf(acc - mx);
  float s = ex;
  for (int off = 32; off; off >>= 1) s += __shfl_xor(s, off);
  emit[((size_t)b * Ll + t) * Ee + e] = ex / s;
}

// total[b] = sum_{t<len} emit[b,t,tag_t] + sum_{1<=t<len} trans[tag_{t-1},tag_t]
__global__ __launch_bounds__(256) void score_kernel(const float* __restrict__ emit,
                                                    const float* __restrict__ trans,
                                                    const int* __restrict__ tags,
                                                    const int* __restrict__ lens,
                                                    float* __restrict__ total) {
  const int b = blockIdx.x;
  const int len = lens[b];
  float part = 0.f;
  for (int t = threadIdx.x; t < len; t += 256) {
    const int tg = tags[b * Ll + t];
    float v = emit[((size_t)b * Ll + t) * Ee + tg];
    if (t >= 1) v += trans[tags[b * Ll + t - 1] * Ee + tg];
    part += v;
  }
  for (int off = 32; off; off >>= 1) part += __shfl_xor(part, off);
  __shared__ float wsum[4];
  if ((threadIdx.x & 63) == 0) wsum[threadIdx.x >> 6] = part;
  __syncthreads();
  if (threadIdx.x == 0) total[b] = wsum[0] + wsum[1] + wsum[2] + wsum[3];
}

// CRF forward scan: one block (one wave) per batch; thread j holds d[j]
__global__ __launch_bounds__(64) void crf_scan(const float* __restrict__ emit,
                                               const float* __restrict__ trans,
                                               const int* __restrict__ lens,
                                               float* __restrict__ dout) {
  const int b = blockIdx.x;
  const int j = threadIdx.x;
  __shared__ float dl[64];
  __shared__ float tr[64 * 64];
  for (int i = j; i < 64 * 64; i += 64) tr[i] = trans[i];
  const int len = lens[b];
  float d = emit[((size_t)b * Ll) * Ee + j];
  __syncthreads();
  for (int t = 1; t < len; t++) {
    dl[j] = d;
    __syncthreads();
    float m = -1e30f;
#pragma unroll 8
    for (int k = 0; k < 64; k++) m = fmaxf(m, dl[k] + tr[k * 64 + j]);
    float s = 0.f;
#pragma unroll 8
    for (int k = 0; k < 64; k++) s += __expf(dl[k] + tr[k * 64 + j] - m);
    d = __logf(s) + m + emit[((size_t)b * Ll + t) * Ee + j];
    __syncthreads();
  }
  dout[b * 64 + j] = d;
}

__global__ __launch_bounds__(64) void final_kernel(const float* __restrict__ dbuf,
                                                   const float* __restrict__ total,
                                                   const int* __restrict__ lens,
                                                   float* __restrict__ out) {
  const int j = threadIdx.x;
  float lsum = 0.f;
  for (int b = 0; b < 32; b++) {
    const float d = dbuf[b * 64 + j];
    float m = d;
    for (int off = 32; off; off >>= 1) m = fmaxf(m, __shfl_xor(m, off));
    const float e = __expf(d - m);
    float s = e;
    for (int off = 32; off; off >>= 1) s += __shfl_xor(s, off);
    const float Z = __logf(s) + m;
    if (j == 0) lsum += -(total[b] - Z) / (float)lens[b];
  }
  if (j == 0) out[0] = lsum / 32.f;
}

// ---------------------------------------------------------------------------
extern "C" void kernel_launch(void* const* d_in, const int* in_sizes, int n_in,
                              void* d_out, int out_size, void* d_ws, size_t ws_size,
                              hipStream_t stream) {
  const float* x = (const float*)d_in[0];
  const int* lens = (const int*)d_in[1];
  const int* tags = (const int*)d_in[2];
  // d_in[3] = mask (derived from lens, unused)
  const float* w_ih_l0 = (const float*)d_in[4];
  const float* w_hh_l0 = (const float*)d_in[5];
  const float* b_l0 = (const float*)d_in[6];
  const float* w_ih_l12 = (const float*)d_in[7];
  const float* w_hh_l12 = (const float*)d_in[8];
  const float* b_l12 = (const float*)d_in[9];
  const float* fc_w = (const float*)d_in[10];
  const float* fc_b = (const float*)d_in[11];
  const float* trans = (const float*)d_in[12];

  char* ws = (char*)d_ws;
  float* xg = (float*)ws;                                   // 2 * 16M floats = 128 MiB
  float* outA = (float*)(ws + 134217728);                   // 32 MiB
  float* outB = (float*)(ws + 167772160);                   // 32 MiB
  float* hstate = (float*)(ws + 201326592);                 // 2*32*256 f32
  float* cstate = (float*)(ws + 201326592 + 65536);
  // CRF buffers alias the (dead-by-then) xg region
  float* emit = (float*)ws;                                 // 4 MiB
  float* total = (float*)(ws + 4194304);
  float* dbuf = total + 32;

  const dim3 ggrid(32, 256);

  // layer 0
  xg_gemm<1024, true><<<ggrid, 256, 0, stream>>>(x, w_ih_l0, b_l0, xg);
  for (int t = 0; t < Ll; t++)
    lstm_step<<<64, 256, 0, stream>>>(w_hh_l0, xg, lens, hstate, cstate, outA, t);

  // layer 1
  xg_gemm<512, false><<<ggrid, 256, 0, stream>>>(outA, w_ih_l12, b_l12, xg);
  for (int t = 0; t < Ll; t++)
    lstm_step<<<64, 256, 0, stream>>>(w_hh_l12, xg, lens, hstate, cstate, outB, t);

  // layer 2
  xg_gemm<512, false><<<ggrid, 256, 0, stream>>>(outB, w_ih_l12 + 2 * 1024 * 512,
                                                 b_l12 + 2 * 1024, xg);
  for (int t = 0; t < Ll; t++)
    lstm_step<<<64, 256, 0, stream>>>(w_hh_l12 + 2 * 1024 * 256, xg, lens, hstate, cstate,
                                      outA, t);

  // CRF
  emit_kernel<<<Ll * Bb, 64, 0, stream>>>(outA, fc_w, fc_b, emit);
  score_kernel<<<Bb, 256, 0, stream>>>(emit, trans, tags, lens, total);
  crf_scan<<<Bb, 64, 0, stream>>>(emit, trans, lens, dbuf);
  final_kernel<<<1, 64, 0, stream>>>(dbuf, total, lens, (float*)d_out);
}

// Round 2
// 39348.016 us; speedup vs baseline: 1.6542x; 1.6542x over previous
//
#include <hip/hip_runtime.h>

#define Bb 32
#define Ll 512
#define Dd 1024
#define Hh 256
#define Ee 64

__device__ __forceinline__ float sigmoidf_(float x) { return 1.f / (1.f + __expf(-x)); }
__device__ __forceinline__ float tanhf_(float x) { return 1.f - 2.f / (__expf(2.f * x) + 1.f); }

// ---------------------------------------------------------------------------
// xg GEMM: out[dir][m][n] = sum_k A[m][k] * W[dir][n][k] + bias[dir][n]
// m = t*B + b (16384 rows), n in [0,1024). XL: A is x with (B,L,D) layout.
// grid: (32, 256) -> blockIdx.x = dir*16 + ntile, blockIdx.y = mtile; 256 thr
// ---------------------------------------------------------------------------
template <int DK, bool XL>
__global__ __launch_bounds__(256) void xg_gemm(const float* __restrict__ A,
                                               const float* __restrict__ W,
                                               const float* __restrict__ bias,
                                               float* __restrict__ xg) {
  const int dir = blockIdx.x >> 4;
  const int n0 = (blockIdx.x & 15) * 64;
  const int m0 = blockIdx.y * 64;
  const float* Wd = W + (size_t)dir * (4 * Hh * DK);
  const float* bd = bias + dir * (4 * Hh);
  float* out = xg + (size_t)dir * ((size_t)Ll * Bb * 4 * Hh);

  __shared__ __align__(16) float As[16][72];
  __shared__ __align__(16) float Bs[16][72];

  const int tid = threadIdx.x;
  const int tm = (tid >> 4) * 4;
  const int tn4 = (tid & 15) * 4;

  float acc[4][4] = {};

  for (int k0 = 0; k0 < DK; k0 += 16) {
    const int r = tid >> 2;
    const int c = (tid & 3) * 4;
    size_t aoff;
    const int m = m0 + r;
    if (XL) {
      const int t = m >> 5, b = m & 31;
      aoff = ((size_t)(b * Ll + t)) * DK + (k0 + c);
    } else {
      aoff = (size_t)m * DK + (k0 + c);
    }
    float4 av = *(const float4*)(A + aoff);
    As[c + 0][r] = av.x; As[c + 1][r] = av.y; As[c + 2][r] = av.z; As[c + 3][r] = av.w;
    float4 wv = *(const float4*)(Wd + (size_t)(n0 + r) * DK + (k0 + c));
    Bs[c + 0][r] = wv.x; Bs[c + 1][r] = wv.y; Bs[c + 2][r] = wv.z; Bs[c + 3][r] = wv.w;
    __syncthreads();

#pragma unroll
    for (int kk = 0; kk < 16; kk++) {
      float4 a4 = *(const float4*)&As[kk][tm];
      float4 b4 = *(const float4*)&Bs[kk][tn4];
      acc[0][0] += a4.x * b4.x; acc[0][1] += a4.x * b4.y; acc[0][2] += a4.x * b4.z; acc[0][3] += a4.x * b4.w;
      acc[1][0] += a4.y * b4.x; acc[1][1] += a4.y * b4.y; acc[1][2] += a4.y * b4.z; acc[1][3] += a4.y * b4.w;
      acc[2][0] += a4.z * b4.x; acc[2][1] += a4.z * b4.y; acc[2][2] += a4.z * b4.z; acc[2][3] += a4.z * b4.w;
      acc[3][0] += a4.w * b4.x; acc[3][1] += a4.w * b4.y; acc[3][2] += a4.w * b4.z; acc[3][3] += a4.w * b4.w;
    }
    __syncthreads();
  }

  const float4 bv = *(const float4*)&bd[n0 + tn4];
#pragma unroll
  for (int i = 0; i < 4; i++) {
    float4 v;
    v.x = acc[i][0] + bv.x; v.y = acc[i][1] + bv.y; v.z = acc[i][2] + bv.z; v.w = acc[i][3] + bv.w;
    *(float4*)&out[(size_t)(m0 + tm + i) * 1024 + n0 + tn4] = v;
  }
}

// ---------------------------------------------------------------------------
// Persistent LSTM layer: one launch runs all 512 steps.
// grid 128 WGs: w = dir(2) x bgroup(4, 8 batches) x jslice(16, 16 ju each)
// block 256: kh(2) x bl(8) x jl(16). W slice (64 rows x 256) LDS-resident.
// h exchanged via global double buffer; sync domain = 16 WGs (same dir,bgroup)
// via monotonic progress flags.
// ---------------------------------------------------------------------------
__global__ __launch_bounds__(256) void lstm_layer(const float* __restrict__ whh,
                                                  const float* __restrict__ xg,
                                                  const int* __restrict__ lens,
                                                  float* __restrict__ hbuf,   // [2][2][32][256]
                                                  float* __restrict__ out,    // (L*B, 512)
                                                  int* __restrict__ progress,
                                                  int base) {
  const int w = blockIdx.x;
  const int dir = w >> 6;
  const int bg = (w >> 4) & 3;
  const int js = w & 15;
  const int tid = threadIdx.x;
  const int jl = tid & 15;
  const int bl = (tid >> 4) & 7;
  const int kh = tid >> 7;

  __shared__ __align__(16) float Wl[64][260];
  __shared__ __align__(16) float hl[8][260];
  __shared__ __align__(16) float4 red[256];

  // load W slice once: row r = g*16 + j2 -> global row g*256 + js*16 + j2
  {
    const float* wd = whh + (size_t)dir * (1024 * 256);
    const int r = tid >> 2;
    const int g = r >> 4, j2 = r & 15;
    const float* src = wd + (size_t)(g * 256 + js * 16 + j2) * 256;
    const int kb = (tid & 3) * 64;
#pragma unroll
    for (int k = 0; k < 64; k += 4)
      *(float4*)&Wl[r][kb + k] = *(const float4*)(src + kb + k);
  }

  const bool fin = (tid < 128);
  const int fb = bg * 8 + bl;          // batch owned (valid for all tids)
  const int ju = js * 16 + jl;
  const int mylen = lens[fb];
  float creg = 0.f;
  __syncthreads();

  const size_t xgbase = (size_t)dir * (512ull * 32 * 1024);
  const int flagbase = w & ~15;        // 16 WGs of (dir,bgroup)

  for (int t = 0; t < 512; ++t) {
    const int tt = dir ? ((t < mylen) ? (mylen - 1 - t) : t) : t;
    // prefetch xg for this step (independent of h / flags)
    const float* xr = xg + xgbase + ((size_t)tt * 32 + fb) * 1024 + ju;
    const float xg0 = xr[0], xg1 = xr[256], xg2 = xr[512], xg3 = xr[768];

    float a0 = 0.f, a1 = 0.f, a2 = 0.f, a3 = 0.f;
    if (t > 0) {
      const int target = base + t;
      for (;;) {
        int v = __hip_atomic_load(progress + flagbase + (tid & 15),
                                  __ATOMIC_RELAXED, __HIP_MEMORY_SCOPE_AGENT);
        if (__all(v >= target)) break;
        __builtin_amdgcn_s_sleep(2);
      }
      __threadfence();   // acquire: invalidate L1 before reading h
      __syncthreads();
      // stage h_{t} (8 batches x 256) from hbuf[t&1]
      {
        const float* hsrc = hbuf + ((size_t)(t & 1) * 2 + dir) * (32 * 256) +
                            (size_t)(bg * 8) * 256;
        const int bi = tid >> 5, kk = (tid & 31) * 8;
        *(float4*)&hl[bi][kk] = *(const float4*)(hsrc + bi * 256 + kk);
        *(float4*)&hl[bi][kk + 4] = *(const float4*)(hsrc + bi * 256 + kk + 4);
      }
      __syncthreads();
      // partial matvec over our K half
      const int k0 = kh * 128;
      float s0 = 0.f, s1 = 0.f, s2 = 0.f, s3 = 0.f;
      const float* hrow = &hl[bl][0];
#pragma unroll 4
      for (int k = k0; k < k0 + 128; k += 4) {
        const float4 h4 = *(const float4*)(hrow + k);
        const float4 w0 = *(const float4*)&Wl[jl][k];
        const float4 w1 = *(const float4*)&Wl[16 + jl][k];
        const float4 w2 = *(const float4*)&Wl[32 + jl][k];
        const float4 w3 = *(const float4*)&Wl[48 + jl][k];
        s0 += h4.x * w0.x + h4.y * w0.y + h4.z * w0.z + h4.w * w0.w;
        s1 += h4.x * w1.x + h4.y * w1.y + h4.z * w1.z + h4.w * w1.w;
        s2 += h4.x * w2.x + h4.y * w2.y + h4.z * w2.z + h4.w * w2.w;
        s3 += h4.x * w3.x + h4.y * w3.y + h4.z * w3.z + h4.w * w3.w;
      }
      red[tid] = make_float4(s0, s1, s2, s3);
      __syncthreads();
      if (fin) {
        const float4 p = red[tid];
        const float4 q = red[tid + 128];
        a0 = p.x + q.x; a1 = p.y + q.y; a2 = p.z + q.z; a3 = p.w + q.w;
      }
    }
    if (fin) {
      a0 += xg0; a1 += xg1; a2 += xg2; a3 += xg3;
      const float ig = sigmoidf_(a0);
      const float fg = sigmoidf_(a1);
      const float gg = tanhf_(a2);
      const float og = sigmoidf_(a3);
      creg = fg * creg + ig * gg;
      const float hnew = og * tanhf_(creg);
      hbuf[((size_t)((t + 1) & 1) * 2 + dir) * (32 * 256) + (size_t)fb * 256 + ju] = hnew;
      out[((size_t)tt * 32 + fb) * 512 + dir * 256 + ju] = (tt < mylen) ? hnew : 0.f;
    }
    __threadfence();   // release: drain h/out stores
    __syncthreads();
    if (tid == 0)
      __hip_atomic_store(progress + w, base + t + 1,
                         __ATOMIC_RELEASE, __HIP_MEMORY_SCOPE_AGENT);
  }
}

// ---------------------------------------------------------------------------
// emit[b][t][e] = softmax_e(out_row(t,b) . fc_w[e] + fc_b[e])
// ---------------------------------------------------------------------------
__global__ __launch_bounds__(64) void emit_kernel(const float* __restrict__ out,
                                                  const float* __restrict__ fcw,
                                                  const float* __restrict__ fcb,
                                                  float* __restrict__ emit) {
  __shared__ __align__(16) float row[512];
  const int e = threadIdx.x;
  const int m = blockIdx.x;           // t*B + b
  const int b = m & 31, t = m >> 5;
  for (int i = e; i < 512; i += 64) row[i] = out[(size_t)m * 512 + i];
  __syncthreads();

  float acc = fcb[e];
  const float* we = fcw + (size_t)e * 512;
#pragma unroll 4
  for (int k = 0; k < 512; k += 4) {
    const float4 r4 = *(const float4*)&row[k];
    const float4 w4 = *(const float4*)(we + k);
    acc += r4.x * w4.x + r4.y * w4.y + r4.z * w4.z + r4.w * w4.w;
  }
  float mx = acc;
  for (int off = 32; off; off >>= 1) mx = fmaxf(mx, __shfl_xor(mx, off));
  const float ex = __expf(acc - mx);
  float s = ex;
  for (int off = 32; off; off >>= 1) s += __shfl_xor(s, off);
  emit[((size_t)b * Ll + t) * Ee + e] = ex / s;
}

__global__ __launch_bounds__(256) void score_kernel(const float* __restrict__ emit,
                                                    const float* __restrict__ trans,
                                                    const int* __restrict__ tags,
                                                    const int* __restrict__ lens,
                                                    float* __restrict__ total) {
  const int b = blockIdx.x;
  const int len = lens[b];
  float part = 0.f;
  for (int t = threadIdx.x; t < len; t += 256) {
    const int tg = tags[b * Ll + t];
    float v = emit[((size_t)b * Ll + t) * Ee + tg];
    if (t >= 1) v += trans[tags[b * Ll + t - 1] * Ee + tg];
    part += v;
  }
  for (int off = 32; off; off >>= 1) part += __shfl_xor(part, off);
  __shared__ float wsum[4];
  if ((threadIdx.x & 63) == 0) wsum[threadIdx.x >> 6] = part;
  __syncthreads();
  if (threadIdx.x == 0) total[b] = wsum[0] + wsum[1] + wsum[2] + wsum[3];
}

__global__ __launch_bounds__(64) void crf_scan(const float* __restrict__ emit,
                                               const float* __restrict__ trans,
                                               const int* __restrict__ lens,
                                               float* __restrict__ dout) {
  const int b = blockIdx.x;
  const int j = threadIdx.x;
  __shared__ float dl[64];
  __shared__ float tr[64 * 64];
  for (int i = j; i < 64 * 64; i += 64) tr[i] = trans[i];
  const int len = lens[b];
  float d = emit[((size_t)b * Ll) * Ee + j];
  __syncthreads();
  for (int t = 1; t < len; t++) {
    dl[j] = d;
    __syncthreads();
    float m = -1e30f;
#pragma unroll 8
    for (int k = 0; k < 64; k++) m = fmaxf(m, dl[k] + tr[k * 64 + j]);
    float s = 0.f;
#pragma unroll 8
    for (int k = 0; k < 64; k++) s += __expf(dl[k] + tr[k * 64 + j] - m);
    d = __logf(s) + m + emit[((size_t)b * Ll + t) * Ee + j];
    __syncthreads();
  }
  dout[b * 64 + j] = d;
}

__global__ __launch_bounds__(64) void final_kernel(const float* __restrict__ dbuf,
                                                   const float* __restrict__ total,
                                                   const int* __restrict__ lens,
                                                   float* __restrict__ out) {
  const int j = threadIdx.x;
  float lsum = 0.f;
  for (int b = 0; b < 32; b++) {
    const float d = dbuf[b * 64 + j];
    float m = d;
    for (int off = 32; off; off >>= 1) m = fmaxf(m, __shfl_xor(m, off));
    const float e = __expf(d - m);
    float s = e;
    for (int off = 32; off; off >>= 1) s += __shfl_xor(s, off);
    const float Z = __logf(s) + m;
    if (j == 0) lsum += -(total[b] - Z) / (float)lens[b];
  }
  if (j == 0) out[0] = lsum / 32.f;
}

// ---------------------------------------------------------------------------
extern "C" void kernel_launch(void* const* d_in, const int* in_sizes, int n_in,
                              void* d_out, int out_size, void* d_ws, size_t ws_size,
                              hipStream_t stream) {
  const float* x = (const float*)d_in[0];
  const int* lens = (const int*)d_in[1];
  const int* tags = (const int*)d_in[2];
  const float* w_ih_l0 = (const float*)d_in[4];
  const float* w_hh_l0 = (const float*)d_in[5];
  const float* b_l0 = (const float*)d_in[6];
  const float* w_ih_l12 = (const float*)d_in[7];
  const float* w_hh_l12 = (const float*)d_in[8];
  const float* b_l12 = (const float*)d_in[9];
  const float* fc_w = (const float*)d_in[10];
  const float* fc_b = (const float*)d_in[11];
  const float* trans = (const float*)d_in[12];

  char* ws = (char*)d_ws;
  float* xg = (float*)ws;                                   // 128 MiB
  float* outA = (float*)(ws + 134217728);                   // 32 MiB
  float* outB = (float*)(ws + 167772160);                   // 32 MiB
  float* hbuf = (float*)(ws + 201326592);                   // 2*2*32*256 f32 = 256 KiB
  int* progress = (int*)(ws + 201326592 + 262144);          // 128 ints
  // CRF buffers alias the (dead-by-then) xg region
  float* emit = (float*)ws;
  float* total = (float*)(ws + 4194304);
  float* dbuf = total + 32;

  hipMemsetAsync(progress, 0, 512, stream);

  const dim3 ggrid(32, 256);

  // layer 0
  xg_gemm<1024, true><<<ggrid, 256, 0, stream>>>(x, w_ih_l0, b_l0, xg);
  lstm_layer<<<128, 256, 0, stream>>>(w_hh_l0, xg, lens, hbuf, outA, progress, 0);

  // layer 1
  xg_gemm<512, false><<<ggrid, 256, 0, stream>>>(outA, w_ih_l12, b_l12, xg);
  lstm_layer<<<128, 256, 0, stream>>>(w_hh_l12, xg, lens, hbuf, outB, progress, 512);

  // layer 2
  xg_gemm<512, false><<<ggrid, 256, 0, stream>>>(outB, w_ih_l12 + 2 * 1024 * 512,
                                                 b_l12 + 2 * 1024, xg);
  lstm_layer<<<128, 256, 0, stream>>>(w_hh_l12 + 2 * 1024 * 256, xg, lens, hbuf, outA,
                                      progress, 1024);

  // CRF
  emit_kernel<<<Ll * Bb, 64, 0, stream>>>(outA, fc_w, fc_b, emit);
  score_kernel<<<Bb, 256, 0, stream>>>(emit, trans, tags, lens, total);
  crf_scan<<<Bb, 64, 0, stream>>>(emit, trans, lens, dbuf);
  final_kernel<<<1, 64, 0, stream>>>(dbuf, total, lens, (float*)d_out);
}

// Round 3
// 13649.716 us; speedup vs baseline: 4.7686x; 2.8827x over previous
//
#include <hip/hip_runtime.h>
#include <hip/hip_fp16.h>

#define Bb 32
#define Ll 512
#define Dd 1024
#define Hh 256
#define Ee 64

__device__ __forceinline__ float sigmoidf_(float x) { return 1.f / (1.f + __expf(-x)); }
__device__ __forceinline__ float tanhf_(float x) { return 1.f - 2.f / (__expf(2.f * x) + 1.f); }

typedef _Float16 f16x2 __attribute__((ext_vector_type(2)));
union Pk16 { uint4 u; f16x2 h2[4]; __half2 hh[4]; };

__device__ __forceinline__ float dot8(uint4 wv, uint4 hv, float acc) {
  Pk16 W, H;
  W.u = wv; H.u = hv;
#if __has_builtin(__builtin_amdgcn_fdot2)
#pragma unroll
  for (int i = 0; i < 4; i++)
    acc = __builtin_amdgcn_fdot2(W.h2[i], H.h2[i], acc, false);
#else
#pragma unroll
  for (int i = 0; i < 4; i++) {
    const float2 wf = __half22float2(W.hh[i]);
    const float2 hf = __half22float2(H.hh[i]);
    acc = fmaf(wf.x, hf.x, acc);
    acc = fmaf(wf.y, hf.y, acc);
  }
#endif
  return acc;
}

// ---------------------------------------------------------------------------
// xg GEMM: out[dir][m][n] = sum_k A[m][k] * W[dir][n][k] + bias[dir][n]
// ---------------------------------------------------------------------------
template <int DK, bool XL>
__global__ __launch_bounds__(256) void xg_gemm(const float* __restrict__ A,
                                               const float* __restrict__ W,
                                               const float* __restrict__ bias,
                                               float* __restrict__ xg) {
  const int dir = blockIdx.x >> 4;
  const int n0 = (blockIdx.x & 15) * 64;
  const int m0 = blockIdx.y * 64;
  const float* Wd = W + (size_t)dir * (4 * Hh * DK);
  const float* bd = bias + dir * (4 * Hh);
  float* out = xg + (size_t)dir * ((size_t)Ll * Bb * 4 * Hh);

  __shared__ __align__(16) float As[16][72];
  __shared__ __align__(16) float Bs[16][72];

  const int tid = threadIdx.x;
  const int tm = (tid >> 4) * 4;
  const int tn4 = (tid & 15) * 4;

  float acc[4][4] = {};

  for (int k0 = 0; k0 < DK; k0 += 16) {
    const int r = tid >> 2;
    const int c = (tid & 3) * 4;
    size_t aoff;
    const int m = m0 + r;
    if (XL) {
      const int t = m >> 5, b = m & 31;
      aoff = ((size_t)(b * Ll + t)) * DK + (k0 + c);
    } else {
      aoff = (size_t)m * DK + (k0 + c);
    }
    float4 av = *(const float4*)(A + aoff);
    As[c + 0][r] = av.x; As[c + 1][r] = av.y; As[c + 2][r] = av.z; As[c + 3][r] = av.w;
    float4 wv = *(const float4*)(Wd + (size_t)(n0 + r) * DK + (k0 + c));
    Bs[c + 0][r] = wv.x; Bs[c + 1][r] = wv.y; Bs[c + 2][r] = wv.z; Bs[c + 3][r] = wv.w;
    __syncthreads();

#pragma unroll
    for (int kk = 0; kk < 16; kk++) {
      float4 a4 = *(const float4*)&As[kk][tm];
      float4 b4 = *(const float4*)&Bs[kk][tn4];
      acc[0][0] += a4.x * b4.x; acc[0][1] += a4.x * b4.y; acc[0][2] += a4.x * b4.z; acc[0][3] += a4.x * b4.w;
      acc[1][0] += a4.y * b4.x; acc[1][1] += a4.y * b4.y; acc[1][2] += a4.y * b4.z; acc[1][3] += a4.y * b4.w;
      acc[2][0] += a4.z * b4.x; acc[2][1] += a4.z * b4.y; acc[2][2] += a4.z * b4.z; acc[2][3] += a4.z * b4.w;
      acc[3][0] += a4.w * b4.x; acc[3][1] += a4.w * b4.y; acc[3][2] += a4.w * b4.z; acc[3][3] += a4.w * b4.w;
    }
    __syncthreads();
  }

  const float4 bv = *(const float4*)&bd[n0 + tn4];
#pragma unroll
  for (int i = 0; i < 4; i++) {
    float4 v;
    v.x = acc[i][0] + bv.x; v.y = acc[i][1] + bv.y; v.z = acc[i][2] + bv.z; v.w = acc[i][3] + bv.w;
    *(float4*)&out[(size_t)(m0 + tm + i) * 1024 + n0 + tn4] = v;
  }
}

// ---------------------------------------------------------------------------
// W_hh -> f16 transposed layout: WT[slice][k8][j][8] halfs
// slice = (layer,dir) flattened; src (slice,1024,256) f32
// grid (128, nslices), 256 thr; idx -> j = idx&1023, k8 = idx>>10
// ---------------------------------------------------------------------------
__global__ __launch_bounds__(256) void conv_w(const float* __restrict__ src,
                                              __half* __restrict__ dst) {
  const int s = blockIdx.y;
  const int idx = blockIdx.x * 256 + threadIdx.x;   // 0..32767
  const int j = idx & 1023;
  const int k8 = idx >> 10;
  const float* sp = src + (size_t)s * 262144 + (size_t)j * 256 + k8 * 8;
  const float4 a = *(const float4*)sp;
  const float4 b = *(const float4*)(sp + 4);
  union { __half h[8]; uint4 u; } o;
  o.h[0] = __float2half(a.x); o.h[1] = __float2half(a.y);
  o.h[2] = __float2half(a.z); o.h[3] = __float2half(a.w);
  o.h[4] = __float2half(b.x); o.h[5] = __float2half(b.y);
  o.h[6] = __float2half(b.z); o.h[7] = __float2half(b.w);
  *(uint4*)(dst + (size_t)s * 262144 + (size_t)k8 * 8192 + (size_t)j * 8) = o.u;
}

// ---------------------------------------------------------------------------
// Sync-free persistent LSTM layer: one WG per (dir, batch) chain.
// grid 64: dir = w>>5, b = w&31. block 256: thread ju owns h-index ju and its
// 4 gate rows. W streamed from L2 (f16, [k8][j][8] layout, coalesced dwordx4);
// h double-buffered in LDS (f16); c in registers. One __syncthreads per step.
// ---------------------------------------------------------------------------
__global__ __launch_bounds__(256) void lstm_layer2(const __half* __restrict__ WT,
                                                   const float* __restrict__ xg,
                                                   const int* __restrict__ lens,
                                                   float* __restrict__ out) {
  const int w = blockIdx.x;
  const int dir = w >> 5;
  const int b = w & 31;
  const int ju = threadIdx.x;

  __shared__ __align__(16) __half h_lds[2][256];
  h_lds[0][ju] = __float2half(0.f);
  __syncthreads();

  const uint4* __restrict__ Wt = (const uint4*)(WT + (size_t)dir * 262144);
  const int mylen = lens[b];
  float c = 0.f;
  const float* xgb = xg + (size_t)dir * (512ull * 32 * 1024) + (size_t)b * 1024 + ju;

  // prefetch xg for t = 0
  {
  }
  int tt0 = dir ? ((0 < mylen) ? (mylen - 1) : 0) : 0;
  const float* xr0 = xgb + (size_t)tt0 * (32 * 1024);
  float p0 = xr0[0], p1 = xr0[256], p2 = xr0[512], p3 = xr0[768];
  int tt = tt0;

  for (int t = 0; t < 512; ++t) {
    float a0 = p0, a1 = p1, a2 = p2, a3 = p3;
    const int tcur = tt;
    // prefetch next step's xg (hides HBM/L3 latency under the dot loop)
    if (t < 511) {
      const int tn = t + 1;
      tt = dir ? ((tn < mylen) ? (mylen - 1 - tn) : tn) : tn;
      const float* xr = xgb + (size_t)tt * (32 * 1024);
      p0 = xr[0]; p1 = xr[256]; p2 = xr[512]; p3 = xr[768];
    }

    const uint4* hp = (const uint4*)&h_lds[t & 1][0];   // 32 x uint4 (8 halfs)
    const uint4* wp = Wt + ju;
#pragma unroll 4
    for (int k8 = 0; k8 < 32; ++k8) {
      const uint4 hv = hp[k8];
      const uint4 w0 = wp[k8 * 1024 + 0];
      const uint4 w1 = wp[k8 * 1024 + 256];
      const uint4 w2 = wp[k8 * 1024 + 512];
      const uint4 w3 = wp[k8 * 1024 + 768];
      a0 = dot8(w0, hv, a0);
      a1 = dot8(w1, hv, a1);
      a2 = dot8(w2, hv, a2);
      a3 = dot8(w3, hv, a3);
    }

    const float ig = sigmoidf_(a0);
    const float fg = sigmoidf_(a1);
    const float gg = tanhf_(a2);
    const float og = sigmoidf_(a3);
    c = fg * c + ig * gg;
    const float hnew = og * tanhf_(c);

    out[((size_t)tcur * 32 + b) * 512 + dir * 256 + ju] = (tcur < mylen) ? hnew : 0.f;
    h_lds[(t + 1) & 1][ju] = __float2half(hnew);
    __syncthreads();
  }
}

// ---------------------------------------------------------------------------
// emit[b][t][e] = softmax_e(out_row(t,b) . fc_w[e] + fc_b[e])
// ---------------------------------------------------------------------------
__global__ __launch_bounds__(64) void emit_kernel(const float* __restrict__ out,
                                                  const float* __restrict__ fcw,
                                                  const float* __restrict__ fcb,
                                                  float* __restrict__ emit) {
  __shared__ __align__(16) float row[512];
  const int e = threadIdx.x;
  const int m = blockIdx.x;           // t*B + b
  const int b = m & 31, t = m >> 5;
  for (int i = e; i < 512; i += 64) row[i] = out[(size_t)m * 512 + i];
  __syncthreads();

  float acc = fcb[e];
  const float* we = fcw + (size_t)e * 512;
#pragma unroll 4
  for (int k = 0; k < 512; k += 4) {
    const float4 r4 = *(const float4*)&row[k];
    const float4 w4 = *(const float4*)(we + k);
    acc += r4.x * w4.x + r4.y * w4.y + r4.z * w4.z + r4.w * w4.w;
  }
  float mx = acc;
  for (int off = 32; off; off >>= 1) mx = fmaxf(mx, __shfl_xor(mx, off));
  const float ex = __expf(acc - mx);
  float s = ex;
  for (int off = 32; off; off >>= 1) s += __shfl_xor(s, off);
  emit[((size_t)b * Ll + t) * Ee + e] = ex / s;
}

__global__ __launch_bounds__(256) void score_kernel(const float* __restrict__ emit,
                                                    const float* __restrict__ trans,
                                                    const int* __restrict__ tags,
                                                    const int* __restrict__ lens,
                                                    float* __restrict__ total) {
  const int b = blockIdx.x;
  const int len = lens[b];
  float part = 0.f;
  for (int t = threadIdx.x; t < len; t += 256) {
    const int tg = tags[b * Ll + t];
    float v = emit[((size_t)b * Ll + t) * Ee + tg];
    if (t >= 1) v += trans[tags[b * Ll + t - 1] * Ee + tg];
    part += v;
  }
  for (int off = 32; off; off >>= 1) part += __shfl_xor(part, off);
  __shared__ float wsum[4];
  if ((threadIdx.x & 63) == 0) wsum[threadIdx.x >> 6] = part;
  __syncthreads();
  if (threadIdx.x == 0) total[b] = wsum[0] + wsum[1] + wsum[2] + wsum[3];
}

__global__ __launch_bounds__(64) void crf_scan(const float* __restrict__ emit,
                                               const float* __restrict__ trans,
                                               const int* __restrict__ lens,
                                               float* __restrict__ dout) {
  const int b = blockIdx.x;
  const int j = threadIdx.x;
  __shared__ float dl[64];
  __shared__ float tr[64 * 64];
  for (int i = j; i < 64 * 64; i += 64) tr[i] = trans[i];
  const int len = lens[b];
  float d = emit[((size_t)b * Ll) * Ee + j];
  __syncthreads();
  for (int t = 1; t < len; t++) {
    dl[j] = d;
    __syncthreads();
    float m = -1e30f;
#pragma unroll 8
    for (int k = 0; k < 64; k++) m = fmaxf(m, dl[k] + tr[k * 64 + j]);
    float s = 0.f;
#pragma unroll 8
    for (int k = 0; k < 64; k++) s += __expf(dl[k] + tr[k * 64 + j] - m);
    d = __logf(s) + m + emit[((size_t)b * Ll + t) * Ee + j];
    __syncthreads();
  }
  dout[b * 64 + j] = d;
}

__global__ __launch_bounds__(64) void final_kernel(const float* __restrict__ dbuf,
                                                   const float* __restrict__ total,
                                                   const int* __restrict__ lens,
                                                   float* __restrict__ out) {
  const int j = threadIdx.x;
  float lsum = 0.f;
  for (int b = 0; b < 32; b++) {
    const float d = dbuf[b * 64 + j];
    float m = d;
    for (int off = 32; off; off >>= 1) m = fmaxf(m, __shfl_xor(m, off));
    const float e = __expf(d - m);
    float s = e;
    for (int off = 32; off; off >>= 1) s += __shfl_xor(s, off);
    const float Z = __logf(s) + m;
    if (j == 0) lsum += -(total[b] - Z) / (float)lens[b];
  }
  if (j == 0) out[0] = lsum / 32.f;
}

// ---------------------------------------------------------------------------
extern "C" void kernel_launch(void* const* d_in, const int* in_sizes, int n_in,
                              void* d_out, int out_size, void* d_ws, size_t ws_size,
                              hipStream_t stream) {
  const float* x = (const float*)d_in[0];
  const int* lens = (const int*)d_in[1];
  const int* tags = (const int*)d_in[2];
  const float* w_ih_l0 = (const float*)d_in[4];
  const float* w_hh_l0 = (const float*)d_in[5];
  const float* b_l0 = (const float*)d_in[6];
  const float* w_ih_l12 = (const float*)d_in[7];
  const float* w_hh_l12 = (const float*)d_in[8];
  const float* b_l12 = (const float*)d_in[9];
  const float* fc_w = (const float*)d_in[10];
  const float* fc_b = (const float*)d_in[11];
  const float* trans = (const float*)d_in[12];

  char* ws = (char*)d_ws;
  float* xg = (float*)ws;                                   // 128 MiB
  float* outA = (float*)(ws + 134217728);                   // 32 MiB
  float* outB = (float*)(ws + 167772160);                   // 32 MiB
  __half* WT = (__half*)(ws + 201326592);                   // 6 * 512 KiB = 3 MiB
  // CRF buffers alias the (dead-by-then) xg region
  float* emit = (float*)ws;
  float* total = (float*)(ws + 4194304);
  float* dbuf = total + 32;

  // one-time weight conversion (f32 -> f16, transposed [k8][j][8] layout)
  conv_w<<<dim3(128, 2), 256, 0, stream>>>(w_hh_l0, WT);
  conv_w<<<dim3(128, 4), 256, 0, stream>>>(w_hh_l12, WT + 2 * 262144);

  const dim3 ggrid(32, 256);

  // layer 0
  xg_gemm<1024, true><<<ggrid, 256, 0, stream>>>(x, w_ih_l0, b_l0, xg);
  lstm_layer2<<<64, 256, 0, stream>>>(WT, xg, lens, outA);

  // layer 1
  xg_gemm<512, false><<<ggrid, 256, 0, stream>>>(outA, w_ih_l12, b_l12, xg);
  lstm_layer2<<<64, 256, 0, stream>>>(WT + 2 * 262144, xg, lens, outB);

  // layer 2
  xg_gemm<512, false><<<ggrid, 256, 0, stream>>>(outB, w_ih_l12 + 2 * 1024 * 512,
                                                 b_l12 + 2 * 1024, xg);
  lstm_layer2<<<64, 256, 0, stream>>>(WT + 4 * 262144, xg, lens, outA);

  // CRF
  emit_kernel<<<Ll * Bb, 64, 0, stream>>>(outA, fc_w, fc_b, emit);
  score_kernel<<<Bb, 256, 0, stream>>>(emit, trans, tags, lens, total);
  crf_scan<<<Bb, 64, 0, stream>>>(emit, trans, lens, dbuf);
  final_kernel<<<1, 64, 0, stream>>>(dbuf, total, lens, (float*)d_out);
}

// Round 4
// 6831.134 us; speedup vs baseline: 9.5285x; 1.9982x over previous
//
#include <hip/hip_runtime.h>
#include <hip/hip_fp16.h>

#define Bb 32
#define Ll 512
#define Dd 1024
#define Hh 256
#define Ee 64

__device__ __forceinline__ float sigmoidf_(float x) { return 1.f / (1.f + __expf(-x)); }
__device__ __forceinline__ float tanhf_(float x) { return 1.f - 2.f / (__expf(2.f * x) + 1.f); }

typedef _Float16 f16x2 __attribute__((ext_vector_type(2)));
typedef _Float16 v8hf __attribute__((ext_vector_type(8)));
typedef float v4f __attribute__((ext_vector_type(4)));
union Pk16 { uint4 u; f16x2 h2[4]; __half2 hh[4]; };

__device__ __forceinline__ float dot8(uint4 wv, uint4 hv, float acc) {
  Pk16 W, H;
  W.u = wv; H.u = hv;
#if __has_builtin(__builtin_amdgcn_fdot2)
#pragma unroll
  for (int i = 0; i < 4; i++)
    acc = __builtin_amdgcn_fdot2(W.h2[i], H.h2[i], acc, false);
#else
#pragma unroll
  for (int i = 0; i < 4; i++) {
    const float2 wf = __half22float2(W.hh[i]);
    const float2 hf = __half22float2(H.hh[i]);
    acc = fmaf(wf.x, hf.x, acc);
    acc = fmaf(wf.y, hf.y, acc);
  }
#endif
  return acc;
}

// ---------------------------------------------------------------------------
// generic f32 -> f16 converter (8 elems/thread)
// ---------------------------------------------------------------------------
__global__ __launch_bounds__(256) void cvt_h(const float* __restrict__ s,
                                             __half* __restrict__ d, int n8) {
  const int i = blockIdx.x * 256 + threadIdx.x;
  if (i >= n8) return;
  const float4 a = ((const float4*)s)[2 * i];
  const float4 b = ((const float4*)s)[2 * i + 1];
  union { __half h[8]; uint4 u; } o;
  o.h[0] = __float2half(a.x); o.h[1] = __float2half(a.y);
  o.h[2] = __float2half(a.z); o.h[3] = __float2half(a.w);
  o.h[4] = __float2half(b.x); o.h[5] = __float2half(b.y);
  o.h[6] = __float2half(b.z); o.h[7] = __float2half(b.w);
  ((uint4*)d)[i] = o.u;
}

// ---------------------------------------------------------------------------
// W_hh -> f16 transposed layout: WT[slice][k8][j][8] halfs
// ---------------------------------------------------------------------------
__global__ __launch_bounds__(256) void conv_w(const float* __restrict__ src,
                                              __half* __restrict__ dst) {
  const int s = blockIdx.y;
  const int idx = blockIdx.x * 256 + threadIdx.x;   // 0..32767
  const int j = idx & 1023;
  const int k8 = idx >> 10;
  const float* sp = src + (size_t)s * 262144 + (size_t)j * 256 + k8 * 8;
  const float4 a = *(const float4*)sp;
  const float4 b = *(const float4*)(sp + 4);
  union { __half h[8]; uint4 u; } o;
  o.h[0] = __float2half(a.x); o.h[1] = __float2half(a.y);
  o.h[2] = __float2half(a.z); o.h[3] = __float2half(a.w);
  o.h[4] = __float2half(b.x); o.h[5] = __float2half(b.y);
  o.h[6] = __float2half(b.z); o.h[7] = __float2half(b.w);
  *(uint4*)(dst + (size_t)s * 262144 + (size_t)k8 * 8192 + (size_t)j * 8) = o.u;
}

// ---------------------------------------------------------------------------
// MFMA f16 GEMM: xg[dir][m][n] = sum_k A[m][k]*W[dir][n][k] + bias[dir][n]
// grid (32, 256): blockIdx.x = dir*16+ntile(64), blockIdx.y = mtile(64)
// block 256 = 4 waves; wave owns 16(m) x 64(n); mfma_f32_16x16x32_f16.
// ---------------------------------------------------------------------------
template <int DK, bool XL>
__global__ __launch_bounds__(256) void xg_gemm_h(const __half* __restrict__ A,
                                                 const __half* __restrict__ W,
                                                 const float* __restrict__ bias,
                                                 __half* __restrict__ xg) {
  const int dir = blockIdx.x >> 4;
  const int n0 = (blockIdx.x & 15) * 64;
  const int m0 = blockIdx.y * 64;
  const __half* Wd = W + (size_t)dir * (1024 * DK);
  const float* bd = bias + dir * 1024;
  __half* out = xg + (size_t)dir * (16384ull * 1024);

  __shared__ __align__(16) __half As[64][40];
  __shared__ __align__(16) __half Bs[64][40];

  const int tid = threadIdx.x;
  const int wave = tid >> 6, lane = tid & 63;
  const int fr = lane & 15, kg = lane >> 4;

  v4f acc[4];
#pragma unroll
  for (int i = 0; i < 4; i++) acc[i] = (v4f)(0.f);

  const int lr = tid >> 2;          // load row 0..63
  const int lc = (tid & 3) * 8;     // k offset
  size_t abase;
  if (XL) {
    const int m = m0 + lr, t = m >> 5, bb = m & 31;
    abase = ((size_t)(bb * 512 + t)) * DK + lc;
  } else {
    abase = (size_t)(m0 + lr) * DK + lc;
  }
  const size_t bbase = (size_t)(n0 + lr) * DK + lc;

  for (int k0 = 0; k0 < DK; k0 += 32) {
    *(uint4*)&As[lr][lc] = *(const uint4*)(A + abase + k0);
    *(uint4*)&Bs[lr][lc] = *(const uint4*)(Wd + bbase + k0);
    __syncthreads();
    const v8hf af = *(const v8hf*)&As[wave * 16 + fr][kg * 8];
#pragma unroll
    for (int nb = 0; nb < 4; ++nb) {
      const v8hf bf = *(const v8hf*)&Bs[nb * 16 + fr][kg * 8];
      acc[nb] = __builtin_amdgcn_mfma_f32_16x16x32_f16(af, bf, acc[nb], 0, 0, 0);
    }
    __syncthreads();
  }

#pragma unroll
  for (int nb = 0; nb < 4; ++nb) {
    const int n = n0 + nb * 16 + fr;
    const float bv = bd[n];
#pragma unroll
    for (int r = 0; r < 4; ++r) {
      const int m = m0 + wave * 16 + kg * 4 + r;
      out[(size_t)m * 1024 + n] = __float2half(acc[nb][r] + bv);
    }
  }
}

// ---------------------------------------------------------------------------
// LSTM layer v3: one WG per (dir,batch) chain; block 1024 = 16 waves.
// tid = kq*256 + ju; kq owns k-quarter (8 k8-slices), ju owns h-index.
// 8 of 32 W k8-slices (2 per quarter) LDS-resident (128KB), rest stream L2.
// LDS float4 reduce across kq; gate math + h/out store on tid<256.
// ---------------------------------------------------------------------------
__global__ __launch_bounds__(1024) void lstm_layer3(const __half* __restrict__ WT,
                                                    const __half* __restrict__ xg,
                                                    const int* __restrict__ lens,
                                                    __half* __restrict__ out) {
  const int w = blockIdx.x, dir = w >> 5, b = w & 31;
  const int tid = threadIdx.x, kq = tid >> 8, ju = tid & 255;

  __shared__ __align__(16) __half Wc[8][1024][8];   // 128 KB: slices kq*8+{0,1}
  __shared__ __align__(16) float4 red[4][256];      // 16 KB
  __shared__ __align__(16) __half h2[2][256];       // 1 KB

  const uint4* __restrict__ Wt = (const uint4*)(WT + (size_t)dir * 262144);
  // preload cached slices: s -> k8 = (s>>1)*8 + (s&1)
#pragma unroll
  for (int s = 0; s < 8; ++s) {
    const int k8 = (s >> 1) * 8 + (s & 1);
    ((uint4*)&Wc[s][0][0])[tid] = Wt[(size_t)k8 * 1024 + tid];
  }
  if (tid < 256) h2[0][tid] = __float2half(0.f);
  const int mylen = lens[b];
  float c = 0.f;

  const __half* xgb = xg + (size_t)dir * (512ull * 32 * 1024) + (size_t)b * 1024 + ju;
  float p0 = 0.f, p1 = 0.f, p2 = 0.f, p3 = 0.f;
  int tt = dir ? (mylen - 1) : 0;
  if (tid < 256) {
    const __half* xr = xgb + (size_t)tt * (32 * 1024);
    p0 = __half2float(xr[0]);   p1 = __half2float(xr[256]);
    p2 = __half2float(xr[512]); p3 = __half2float(xr[768]);
  }
  __syncthreads();

  for (int t = 0; t < 512; ++t) {
    const int tcur = tt;
    const uint4* hp = (const uint4*)&h2[t & 1][0];
    float a0 = 0.f, a1 = 0.f, a2 = 0.f, a3 = 0.f;
    // LDS-cached slices (s = 0,1)
#pragma unroll
    for (int s = 0; s < 2; ++s) {
      const int k8 = kq * 8 + s;
      const uint4 hv = hp[k8];
      const uint4* wrow = (const uint4*)&Wc[kq * 2 + s][0][0];
      a0 = dot8(wrow[0 * 256 + ju], hv, a0);
      a1 = dot8(wrow[1 * 256 + ju], hv, a1);
      a2 = dot8(wrow[2 * 256 + ju], hv, a2);
      a3 = dot8(wrow[3 * 256 + ju], hv, a3);
    }
    // streamed slices (s = 2..7)
#pragma unroll
    for (int s = 2; s < 8; ++s) {
      const int k8 = kq * 8 + s;
      const uint4 hv = hp[k8];
      const uint4* wp = Wt + (size_t)k8 * 1024 + ju;
      a0 = dot8(wp[0], hv, a0);
      a1 = dot8(wp[256], hv, a1);
      a2 = dot8(wp[512], hv, a2);
      a3 = dot8(wp[768], hv, a3);
    }
    red[kq][ju] = make_float4(a0, a1, a2, a3);
    __syncthreads();
    if (tid < 256) {
      const float4 r0 = red[0][tid], r1 = red[1][tid];
      const float4 r2 = red[2][tid], r3 = red[3][tid];
      float g0 = r0.x + r1.x + r2.x + r3.x + p0;
      float g1 = r0.y + r1.y + r2.y + r3.y + p1;
      float g2 = r0.z + r1.z + r2.z + r3.z + p2;
      float g3 = r0.w + r1.w + r2.w + r3.w + p3;
      if (t < 511) {
        const int tn = t + 1;
        tt = dir ? ((tn < mylen) ? (mylen - 1 - tn) : tn) : tn;
        const __half* xr = xgb + (size_t)tt * (32 * 1024);
        p0 = __half2float(xr[0]);   p1 = __half2float(xr[256]);
        p2 = __half2float(xr[512]); p3 = __half2float(xr[768]);
      }
      const float ig = sigmoidf_(g0);
      const float fg = sigmoidf_(g1);
      const float gg = tanhf_(g2);
      const float og = sigmoidf_(g3);
      c = fg * c + ig * gg;
      const float hnew = og * tanhf_(c);
      out[((size_t)tcur * 32 + b) * 512 + dir * 256 + tid] =
          __float2half((tcur < mylen) ? hnew : 0.f);
      h2[(t + 1) & 1][tid] = __float2half(hnew);
    }
    __syncthreads();
  }
}

// ---------------------------------------------------------------------------
// emit[b][t][e] = softmax_e(out_row(t,b) . fc_w[e] + fc_b[e]); out is f16
// ---------------------------------------------------------------------------
__global__ __launch_bounds__(64) void emit_kernel(const __half* __restrict__ out,
                                                  const float* __restrict__ fcw,
                                                  const float* __restrict__ fcb,
                                                  float* __restrict__ emit) {
  __shared__ __align__(16) __half row[512];
  const int e = threadIdx.x;
  const int m = blockIdx.x;           // t*B + b
  const int b = m & 31, t = m >> 5;
  ((uint4*)row)[e] = ((const uint4*)(out + (size_t)m * 512))[e];
  __syncthreads();

  float acc = fcb[e];
  const float* we = fcw + (size_t)e * 512;
  const __half2* r2 = (const __half2*)row;
#pragma unroll 8
  for (int k = 0; k < 256; ++k) {
    const float2 h = __half22float2(r2[k]);
    const float2 wv = *(const float2*)(we + 2 * k);
    acc = fmaf(h.x, wv.x, fmaf(h.y, wv.y, acc));
  }
  float mx = acc;
  for (int off = 32; off; off >>= 1) mx = fmaxf(mx, __shfl_xor(mx, off));
  const float ex = __expf(acc - mx);
  float s = ex;
  for (int off = 32; off; off >>= 1) s += __shfl_xor(s, off);
  emit[((size_t)b * Ll + t) * Ee + e] = ex / s;
}

__global__ __launch_bounds__(256) void score_kernel(const float* __restrict__ emit,
                                                    const float* __restrict__ trans,
                                                    const int* __restrict__ tags,
                                                    const int* __restrict__ lens,
                                                    float* __restrict__ total) {
  const int b = blockIdx.x;
  const int len = lens[b];
  float part = 0.f;
  for (int t = threadIdx.x; t < len; t += 256) {
    const int tg = tags[b * Ll + t];
    float v = emit[((size_t)b * Ll + t) * Ee + tg];
    if (t >= 1) v += trans[tags[b * Ll + t - 1] * Ee + tg];
    part += v;
  }
  for (int off = 32; off; off >>= 1) part += __shfl_xor(part, off);
  __shared__ float wsum[4];
  if ((threadIdx.x & 63) == 0) wsum[threadIdx.x >> 6] = part;
  __syncthreads();
  if (threadIdx.x == 0) total[b] = wsum[0] + wsum[1] + wsum[2] + wsum[3];
}

__global__ __launch_bounds__(64) void crf_scan(const float* __restrict__ emit,
                                               const float* __restrict__ trans,
                                               const int* __restrict__ lens,
                                               float* __restrict__ dout) {
  const int b = blockIdx.x;
  const int j = threadIdx.x;
  __shared__ float dl[64];
  __shared__ float tr[64 * 64];
  for (int i = j; i < 64 * 64; i += 64) tr[i] = trans[i];
  const int len = lens[b];
  float d = emit[((size_t)b * Ll) * Ee + j];
  __syncthreads();
  for (int t = 1; t < len; t++) {
    dl[j] = d;
    __syncthreads();
    float m = -1e30f;
#pragma unroll 8
    for (int k = 0; k < 64; k++) m = fmaxf(m, dl[k] + tr[k * 64 + j]);
    float s = 0.f;
#pragma unroll 8
    for (int k = 0; k < 64; k++) s += __expf(dl[k] + tr[k * 64 + j] - m);
    d = __logf(s) + m + emit[((size_t)b * Ll + t) * Ee + j];
    __syncthreads();
  }
  dout[b * 64 + j] = d;
}

__global__ __launch_bounds__(64) void final_kernel(const float* __restrict__ dbuf,
                                                   const float* __restrict__ total,
                                                   const int* __restrict__ lens,
                                                   float* __restrict__ out) {
  const int j = threadIdx.x;
  float lsum = 0.f;
  for (int b = 0; b < 32; b++) {
    const float d = dbuf[b * 64 + j];
    float m = d;
    for (int off = 32; off; off >>= 1) m = fmaxf(m, __shfl_xor(m, off));
    const float e = __expf(d - m);
    float s = e;
    for (int off = 32; off; off >>= 1) s += __shfl_xor(s, off);
    const float Z = __logf(s) + m;
    if (j == 0) lsum += -(total[b] - Z) / (float)lens[b];
  }
  if (j == 0) out[0] = lsum / 32.f;
}

// ---------------------------------------------------------------------------
extern "C" void kernel_launch(void* const* d_in, const int* in_sizes, int n_in,
                              void* d_out, int out_size, void* d_ws, size_t ws_size,
                              hipStream_t stream) {
  const float* x = (const float*)d_in[0];
  const int* lens = (const int*)d_in[1];
  const int* tags = (const int*)d_in[2];
  const float* w_ih_l0 = (const float*)d_in[4];
  const float* w_hh_l0 = (const float*)d_in[5];
  const float* b_l0 = (const float*)d_in[6];
  const float* w_ih_l12 = (const float*)d_in[7];
  const float* w_hh_l12 = (const float*)d_in[8];
  const float* b_l12 = (const float*)d_in[9];
  const float* fc_w = (const float*)d_in[10];
  const float* fc_b = (const float*)d_in[11];
  const float* trans = (const float*)d_in[12];

  char* ws = (char*)d_ws;
  __half* xg = (__half*)ws;                          // 64 MiB (2 x 16384 x 1024 f16)
  __half* xh = (__half*)(ws + 67108864);             // 32 MiB (x as f16)
  __half* outA = (__half*)(ws + 100663296);          // 16 MiB
  __half* outB = (__half*)(ws + 117440512);          // 16 MiB
  __half* WT = (__half*)(ws + 134217728);            // 3 MiB (whh f16 transposed)
  __half* WIH0 = (__half*)(ws + 137363456);          // 4 MiB
  __half* WIH12 = (__half*)(ws + 141557760);         // 4 MiB
  // CRF buffers alias the (dead-by-then) xg region
  float* emit = (float*)ws;                          // 4 MiB
  float* total = (float*)(ws + 4194304);
  float* dbuf = total + 32;

  // one-time conversions
  cvt_h<<<8192, 256, 0, stream>>>(x, xh, 2097152);             // x f32 -> f16
  cvt_h<<<1024, 256, 0, stream>>>(w_ih_l0, WIH0, 262144);      // 2x1024x1024
  cvt_h<<<1024, 256, 0, stream>>>(w_ih_l12, WIH12, 262144);    // 4x1024x512
  conv_w<<<dim3(128, 2), 256, 0, stream>>>(w_hh_l0, WT);
  conv_w<<<dim3(128, 4), 256, 0, stream>>>(w_hh_l12, WT + 2 * 262144);

  const dim3 ggrid(32, 256);

  // layer 0
  xg_gemm_h<1024, true><<<ggrid, 256, 0, stream>>>(xh, WIH0, b_l0, xg);
  lstm_layer3<<<64, 1024, 0, stream>>>(WT, xg, lens, outA);

  // layer 1
  xg_gemm_h<512, false><<<ggrid, 256, 0, stream>>>(outA, WIH12, b_l12, xg);
  lstm_layer3<<<64, 1024, 0, stream>>>(WT + 2 * 262144, xg, lens, outB);

  // layer 2
  xg_gemm_h<512, false><<<ggrid, 256, 0, stream>>>(outB, WIH12 + 2 * 1024 * 512,
                                                   b_l12 + 2 * 1024, xg);
  lstm_layer3<<<64, 1024, 0, stream>>>(WT + 4 * 262144, xg, lens, outA);

  // CRF
  emit_kernel<<<Ll * Bb, 64, 0, stream>>>(outA, fc_w, fc_b, emit);
  score_kernel<<<Bb, 256, 0, stream>>>(emit, trans, tags, lens, total);
  crf_scan<<<Bb, 64, 0, stream>>>(emit, trans, lens, dbuf);
  final_kernel<<<1, 64, 0, stream>>>(dbuf, total, lens, (float*)d_out);
}

// Round 5
// 5291.906 us; speedup vs baseline: 12.3000x; 1.2909x over previous
//
#include <hip/hip_runtime.h>
#include <hip/hip_fp16.h>

#define Bb 32
#define Ll 512
#define Dd 1024
#define Hh 256
#define Ee 64

__device__ __forceinline__ float sigmoidf_(float x) { return 1.f / (1.f + __expf(-x)); }
__device__ __forceinline__ float tanhf_(float x) { return 1.f - 2.f / (__expf(2.f * x) + 1.f); }

typedef _Float16 f16x2 __attribute__((ext_vector_type(2)));
typedef _Float16 v8hf __attribute__((ext_vector_type(8)));
typedef float v4f __attribute__((ext_vector_type(4)));
union Pk16 { uint4 u; f16x2 h2[4]; __half2 hh[4]; };

__device__ __forceinline__ float dot8(uint4 wv, uint4 hv, float acc) {
  Pk16 W, H;
  W.u = wv; H.u = hv;
#if __has_builtin(__builtin_amdgcn_fdot2)
#pragma unroll
  for (int i = 0; i < 4; i++)
    acc = __builtin_amdgcn_fdot2(W.h2[i], H.h2[i], acc, false);
#else
#pragma unroll
  for (int i = 0; i < 4; i++) {
    const float2 wf = __half22float2(W.hh[i]);
    const float2 hf = __half22float2(H.hh[i]);
    acc = fmaf(wf.x, hf.x, acc);
    acc = fmaf(wf.y, hf.y, acc);
  }
#endif
  return acc;
}

// ---------------------------------------------------------------------------
// generic f32 -> f16 converter (8 elems/thread)
// ---------------------------------------------------------------------------
__global__ __launch_bounds__(256) void cvt_h(const float* __restrict__ s,
                                             __half* __restrict__ d, int n8) {
  const int i = blockIdx.x * 256 + threadIdx.x;
  if (i >= n8) return;
  const float4 a = ((const float4*)s)[2 * i];
  const float4 b = ((const float4*)s)[2 * i + 1];
  union { __half h[8]; uint4 u; } o;
  o.h[0] = __float2half(a.x); o.h[1] = __float2half(a.y);
  o.h[2] = __float2half(a.z); o.h[3] = __float2half(a.w);
  o.h[4] = __float2half(b.x); o.h[5] = __float2half(b.y);
  o.h[6] = __float2half(b.z); o.h[7] = __float2half(b.w);
  ((uint4*)d)[i] = o.u;
}

// ---------------------------------------------------------------------------
// W_hh -> f16 transposed layout: WT[slice][k8][row][8] halfs (row = gate*256+j)
// ---------------------------------------------------------------------------
__global__ __launch_bounds__(256) void conv_w(const float* __restrict__ src,
                                              __half* __restrict__ dst) {
  const int s = blockIdx.y;
  const int idx = blockIdx.x * 256 + threadIdx.x;   // 0..32767
  const int j = idx & 1023;
  const int k8 = idx >> 10;
  const float* sp = src + (size_t)s * 262144 + (size_t)j * 256 + k8 * 8;
  const float4 a = *(const float4*)sp;
  const float4 b = *(const float4*)(sp + 4);
  union { __half h[8]; uint4 u; } o;
  o.h[0] = __float2half(a.x); o.h[1] = __float2half(a.y);
  o.h[2] = __float2half(a.z); o.h[3] = __float2half(a.w);
  o.h[4] = __float2half(b.x); o.h[5] = __float2half(b.y);
  o.h[6] = __float2half(b.z); o.h[7] = __float2half(b.w);
  *(uint4*)(dst + (size_t)s * 262144 + (size_t)k8 * 8192 + (size_t)j * 8) = o.u;
}

// ---------------------------------------------------------------------------
// MFMA f16 GEMM: xg[dir][m][n] = sum_k A[m][k]*W[dir][n][k] + bias[dir][n]
// ---------------------------------------------------------------------------
template <int DK, bool XL>
__global__ __launch_bounds__(256) void xg_gemm_h(const __half* __restrict__ A,
                                                 const __half* __restrict__ W,
                                                 const float* __restrict__ bias,
                                                 __half* __restrict__ xg) {
  const int dir = blockIdx.x >> 4;
  const int n0 = (blockIdx.x & 15) * 64;
  const int m0 = blockIdx.y * 64;
  const __half* Wd = W + (size_t)dir * (1024 * DK);
  const float* bd = bias + dir * 1024;
  __half* out = xg + (size_t)dir * (16384ull * 1024);

  __shared__ __align__(16) __half As[64][40];
  __shared__ __align__(16) __half Bs[64][40];

  const int tid = threadIdx.x;
  const int wave = tid >> 6, lane = tid & 63;
  const int fr = lane & 15, kg = lane >> 4;

  v4f acc[4];
#pragma unroll
  for (int i = 0; i < 4; i++) acc[i] = (v4f)(0.f);

  const int lr = tid >> 2;          // load row 0..63
  const int lc = (tid & 3) * 8;     // k offset
  size_t abase;
  if (XL) {
    const int m = m0 + lr, t = m >> 5, bb = m & 31;
    abase = ((size_t)(bb * 512 + t)) * DK + lc;
  } else {
    abase = (size_t)(m0 + lr) * DK + lc;
  }
  const size_t bbase = (size_t)(n0 + lr) * DK + lc;

  for (int k0 = 0; k0 < DK; k0 += 32) {
    *(uint4*)&As[lr][lc] = *(const uint4*)(A + abase + k0);
    *(uint4*)&Bs[lr][lc] = *(const uint4*)(Wd + bbase + k0);
    __syncthreads();
    const v8hf af = *(const v8hf*)&As[wave * 16 + fr][kg * 8];
#pragma unroll
    for (int nb = 0; nb < 4; ++nb) {
      const v8hf bf = *(const v8hf*)&Bs[nb * 16 + fr][kg * 8];
      acc[nb] = __builtin_amdgcn_mfma_f32_16x16x32_f16(af, bf, acc[nb], 0, 0, 0);
    }
    __syncthreads();
  }

#pragma unroll
  for (int nb = 0; nb < 4; ++nb) {
    const int n = n0 + nb * 16 + fr;
    const float bv = bd[n];
#pragma unroll
    for (int r = 0; r < 4; ++r) {
      const int m = m0 + wave * 16 + kg * 4 + r;
      out[(size_t)m * 1024 + n] = __float2half(acc[nb][r] + bv);
    }
  }
}

// ---------------------------------------------------------------------------
// LSTM layer v4: one WG per (dir,batch) chain; block 1024, gate-split.
// tid = g*256 + j: thread computes the FULL k=256 dot for gate row g*256+j.
// W slices (k8 = 0..31): 0..8 LDS-cached (144 KB), 9..16 register-cached
// (8 x uint4 = 32 VGPR), 17..31 streamed from L2 (240 KB/step).
// Gate exchange via 4 KB LDS; h double-buffered f16 in LDS.
// ---------------------------------------------------------------------------
__global__ __launch_bounds__(1024) void lstm_layer4(const __half* __restrict__ WT,
                                                    const __half* __restrict__ xg,
                                                    const int* __restrict__ lens,
                                                    __half* __restrict__ out) {
  const int w = blockIdx.x, dir = w >> 5, b = w & 31;
  const int tid = threadIdx.x, g = tid >> 8, j = tid & 255;
  (void)g;

  __shared__ __align__(16) __half Wc[9][1024][8];   // 144 KB
  __shared__ __align__(16) float aex[4][256];       // 4 KB
  __shared__ __align__(16) __half h2[2][256];       // 1 KB

  const uint4* __restrict__ Wt = (const uint4*)(WT + (size_t)dir * 262144);
  // preload LDS slices 0..8
#pragma unroll
  for (int s = 0; s < 9; ++s)
    ((uint4*)&Wc[s][0][0])[tid] = Wt[(size_t)s * 1024 + tid];
  // register-cached slices 9..16
  const uint4 r0 = Wt[9 * 1024 + tid];
  const uint4 r1 = Wt[10 * 1024 + tid];
  const uint4 r2 = Wt[11 * 1024 + tid];
  const uint4 r3 = Wt[12 * 1024 + tid];
  const uint4 r4 = Wt[13 * 1024 + tid];
  const uint4 r5 = Wt[14 * 1024 + tid];
  const uint4 r6 = Wt[15 * 1024 + tid];
  const uint4 r7 = Wt[16 * 1024 + tid];

  if (tid < 256) h2[0][tid] = __float2half(0.f);
  const int mylen = lens[b];
  float c = 0.f;

  const __half* xgb = xg + (size_t)dir * (512ull * 32 * 1024) + (size_t)b * 1024 + j;
  float p0 = 0.f, p1 = 0.f, p2 = 0.f, p3 = 0.f;
  int tt = dir ? (mylen - 1) : 0;
  if (tid < 256) {
    const __half* xr = xgb + (size_t)tt * (32 * 1024);
    p0 = __half2float(xr[0]);   p1 = __half2float(xr[256]);
    p2 = __half2float(xr[512]); p3 = __half2float(xr[768]);
  }
  __syncthreads();

  for (int t = 0; t < 512; ++t) {
    const int tcur = tt;
    const uint4* hp = (const uint4*)&h2[t & 1][0];
    float a = 0.f;
    // streamed slices 17..31 (loads hoisted/pipelined by compiler)
#pragma unroll
    for (int s = 17; s < 32; ++s) {
      const uint4 sv = Wt[(size_t)s * 1024 + tid];
      a = dot8(sv, hp[s], a);
    }
    // LDS-cached slices 0..8
#pragma unroll
    for (int s = 0; s < 9; ++s)
      a = dot8(((const uint4*)&Wc[s][0][0])[tid], hp[s], a);
    // register-cached slices 9..16
    a = dot8(r0, hp[9], a);
    a = dot8(r1, hp[10], a);
    a = dot8(r2, hp[11], a);
    a = dot8(r3, hp[12], a);
    a = dot8(r4, hp[13], a);
    a = dot8(r5, hp[14], a);
    a = dot8(r6, hp[15], a);
    a = dot8(r7, hp[16], a);

    aex[tid >> 8][tid & 255] = a;
    __syncthreads();
    if (tid < 256) {
      float g0 = aex[0][tid] + p0;
      float g1 = aex[1][tid] + p1;
      float g2 = aex[2][tid] + p2;
      float g3 = aex[3][tid] + p3;
      if (t < 511) {
        const int tn = t + 1;
        tt = dir ? ((tn < mylen) ? (mylen - 1 - tn) : tn) : tn;
        const __half* xr = xgb + (size_t)tt * (32 * 1024);
        p0 = __half2float(xr[0]);   p1 = __half2float(xr[256]);
        p2 = __half2float(xr[512]); p3 = __half2float(xr[768]);
      }
      const float ig = sigmoidf_(g0);
      const float fg = sigmoidf_(g1);
      const float gg = tanhf_(g2);
      const float og = sigmoidf_(g3);
      c = fg * c + ig * gg;
      const float hnew = og * tanhf_(c);
      out[((size_t)tcur * 32 + b) * 512 + dir * 256 + tid] =
          __float2half((tcur < mylen) ? hnew : 0.f);
      h2[(t + 1) & 1][tid] = __float2half(hnew);
    }
    __syncthreads();
  }
}

// ---------------------------------------------------------------------------
// emit[b][t][e] = softmax_e(out_row(t,b) . fc_w[e] + fc_b[e]); out is f16
// ---------------------------------------------------------------------------
__global__ __launch_bounds__(64) void emit_kernel(const __half* __restrict__ out,
                                                  const float* __restrict__ fcw,
                                                  const float* __restrict__ fcb,
                                                  float* __restrict__ emit) {
  __shared__ __align__(16) __half row[512];
  const int e = threadIdx.x;
  const int m = blockIdx.x;           // t*B + b
  const int b = m & 31, t = m >> 5;
  ((uint4*)row)[e] = ((const uint4*)(out + (size_t)m * 512))[e];
  __syncthreads();

  float acc = fcb[e];
  const float* we = fcw + (size_t)e * 512;
  const __half2* r2 = (const __half2*)row;
#pragma unroll 8
  for (int k = 0; k < 256; ++k) {
    const float2 h = __half22float2(r2[k]);
    const float2 wv = *(const float2*)(we + 2 * k);
    acc = fmaf(h.x, wv.x, fmaf(h.y, wv.y, acc));
  }
  float mx = acc;
  for (int off = 32; off; off >>= 1) mx = fmaxf(mx, __shfl_xor(mx, off));
  const float ex = __expf(acc - mx);
  float s = ex;
  for (int off = 32; off; off >>= 1) s += __shfl_xor(s, off);
  emit[((size_t)b * Ll + t) * Ee + e] = ex / s;
}

__global__ __launch_bounds__(256) void score_kernel(const float* __restrict__ emit,
                                                    const float* __restrict__ trans,
                                                    const int* __restrict__ tags,
                                                    const int* __restrict__ lens,
                                                    float* __restrict__ total) {
  const int b = blockIdx.x;
  const int len = lens[b];
  float part = 0.f;
  for (int t = threadIdx.x; t < len; t += 256) {
    const int tg = tags[b * Ll + t];
    float v = emit[((size_t)b * Ll + t) * Ee + tg];
    if (t >= 1) v += trans[tags[b * Ll + t - 1] * Ee + tg];
    part += v;
  }
  for (int off = 32; off; off >>= 1) part += __shfl_xor(part, off);
  __shared__ float wsum[4];
  if ((threadIdx.x & 63) == 0) wsum[threadIdx.x >> 6] = part;
  __syncthreads();
  if (threadIdx.x == 0) total[b] = wsum[0] + wsum[1] + wsum[2] + wsum[3];
}

// ---------------------------------------------------------------------------
// CRF prep: cm[j] = max_k trans[k][j]; E[j][k] = exp(trans[k][j] - cm[j])
// ---------------------------------------------------------------------------
__global__ __launch_bounds__(64) void crf_prep(const float* __restrict__ trans,
                                               float* __restrict__ E,
                                               float* __restrict__ cm) {
  const int j = threadIdx.x;
  float m = -1e30f;
  for (int k = 0; k < 64; k++) m = fmaxf(m, trans[k * 64 + j]);
  cm[j] = m;
  for (int k = 0; k < 64; k++) E[j * 64 + k] = __expf(trans[k * 64 + j] - m);
}

// ---------------------------------------------------------------------------
// CRF scan v2 (factorized): d_new[j] = log(sum_k e_k * E[j][k]) + maxd + cm[j]
// + emit[t][j], with e_k = exp(d_k - maxd). One wave per batch; E in VGPRs.
// ---------------------------------------------------------------------------
__global__ __launch_bounds__(64) void crf_scan2(const float* __restrict__ emit,
                                                const float* __restrict__ E,
                                                const float* __restrict__ cm,
                                                const int* __restrict__ lens,
                                                float* __restrict__ dout) {
  const int b = blockIdx.x, j = threadIdx.x;
  __shared__ float el[2][64];
  float Er[64];
#pragma unroll
  for (int kc = 0; kc < 16; ++kc) {
    const float4 v = *(const float4*)(E + j * 64 + 4 * kc);
    Er[4 * kc + 0] = v.x; Er[4 * kc + 1] = v.y;
    Er[4 * kc + 2] = v.z; Er[4 * kc + 3] = v.w;
  }
  const float cmj = cm[j];
  const int len = lens[b];
  const float* eb = emit + (size_t)b * 512 * 64 + j;
  float d = eb[0];
  float enext = (len > 1) ? eb[64] : 0.f;

  for (int t = 1; t < len; ++t) {
    float m = d;
#pragma unroll
    for (int off = 32; off; off >>= 1) m = fmaxf(m, __shfl_xor(m, off));
    const float ej = __expf(d - m);
    el[t & 1][j] = ej;
    const float emt = enext;
    if (t + 1 < len) enext = eb[(size_t)(t + 1) * 64];
    __syncthreads();
    float s0 = 0.f, s1 = 0.f, s2 = 0.f, s3 = 0.f;
    const float4* e4 = (const float4*)&el[t & 1][0];
#pragma unroll
    for (int kc = 0; kc < 16; ++kc) {
      const float4 ev = e4[kc];
      s0 = fmaf(ev.x, Er[4 * kc + 0], s0);
      s1 = fmaf(ev.y, Er[4 * kc + 1], s1);
      s2 = fmaf(ev.z, Er[4 * kc + 2], s2);
      s3 = fmaf(ev.w, Er[4 * kc + 3], s3);
    }
    d = __logf((s0 + s1) + (s2 + s3)) + m + cmj + emt;
    __syncthreads();
  }
  dout[b * 64 + j] = d;
}

__global__ __launch_bounds__(64) void final_kernel(const float* __restrict__ dbuf,
                                                   const float* __restrict__ total,
                                                   const int* __restrict__ lens,
                                                   float* __restrict__ out) {
  const int j = threadIdx.x;
  float lsum = 0.f;
  for (int b = 0; b < 32; b++) {
    const float d = dbuf[b * 64 + j];
    float m = d;
    for (int off = 32; off; off >>= 1) m = fmaxf(m, __shfl_xor(m, off));
    const float e = __expf(d - m);
    float s = e;
    for (int off = 32; off; off >>= 1) s += __shfl_xor(s, off);
    const float Z = __logf(s) + m;
    if (j == 0) lsum += -(total[b] - Z) / (float)lens[b];
  }
  if (j == 0) out[0] = lsum / 32.f;
}

// ---------------------------------------------------------------------------
extern "C" void kernel_launch(void* const* d_in, const int* in_sizes, int n_in,
                              void* d_out, int out_size, void* d_ws, size_t ws_size,
                              hipStream_t stream) {
  const float* x = (const float*)d_in[0];
  const int* lens = (const int*)d_in[1];
  const int* tags = (const int*)d_in[2];
  const float* w_ih_l0 = (const float*)d_in[4];
  const float* w_hh_l0 = (const float*)d_in[5];
  const float* b_l0 = (const float*)d_in[6];
  const float* w_ih_l12 = (const float*)d_in[7];
  const float* w_hh_l12 = (const float*)d_in[8];
  const float* b_l12 = (const float*)d_in[9];
  const float* fc_w = (const float*)d_in[10];
  const float* fc_b = (const float*)d_in[11];
  const float* trans = (const float*)d_in[12];

  char* ws = (char*)d_ws;
  __half* xg = (__half*)ws;                          // 64 MiB
  __half* xh = (__half*)(ws + 67108864);             // 32 MiB
  __half* outA = (__half*)(ws + 100663296);          // 16 MiB
  __half* outB = (__half*)(ws + 117440512);          // 16 MiB
  __half* WT = (__half*)(ws + 134217728);            // 3 MiB
  __half* WIH0 = (__half*)(ws + 137363456);          // 4 MiB
  __half* WIH12 = (__half*)(ws + 141557760);         // 4 MiB
  float* Ebuf = (float*)(ws + 145752064);            // 16 KiB
  float* cmbuf = (float*)(ws + 145768448);           // 256 B
  // CRF buffers alias the (dead-by-then) xg region
  float* emit = (float*)ws;                          // 4 MiB
  float* total = (float*)(ws + 4194304);
  float* dbuf = total + 32;

  // one-time conversions + CRF prep
  cvt_h<<<8192, 256, 0, stream>>>(x, xh, 2097152);
  cvt_h<<<1024, 256, 0, stream>>>(w_ih_l0, WIH0, 262144);
  cvt_h<<<1024, 256, 0, stream>>>(w_ih_l12, WIH12, 262144);
  conv_w<<<dim3(128, 2), 256, 0, stream>>>(w_hh_l0, WT);
  conv_w<<<dim3(128, 4), 256, 0, stream>>>(w_hh_l12, WT + 2 * 262144);
  crf_prep<<<1, 64, 0, stream>>>(trans, Ebuf, cmbuf);

  const dim3 ggrid(32, 256);

  // layer 0
  xg_gemm_h<1024, true><<<ggrid, 256, 0, stream>>>(xh, WIH0, b_l0, xg);
  lstm_layer4<<<64, 1024, 0, stream>>>(WT, xg, lens, outA);

  // layer 1
  xg_gemm_h<512, false><<<ggrid, 256, 0, stream>>>(outA, WIH12, b_l12, xg);
  lstm_layer4<<<64, 1024, 0, stream>>>(WT + 2 * 262144, xg, lens, outB);

  // layer 2
  xg_gemm_h<512, false><<<ggrid, 256, 0, stream>>>(outB, WIH12 + 2 * 1024 * 512,
                                                   b_l12 + 2 * 1024, xg);
  lstm_layer4<<<64, 1024, 0, stream>>>(WT + 4 * 262144, xg, lens, outA);

  // CRF
  emit_kernel<<<Ll * Bb, 64, 0, stream>>>(outA, fc_w, fc_b, emit);
  score_kernel<<<Bb, 256, 0, stream>>>(emit, trans, tags, lens, total);
  crf_scan2<<<Bb, 64, 0, stream>>>(emit, Ebuf, cmbuf, lens, dbuf);
  final_kernel<<<1, 64, 0, stream>>>(dbuf, total, lens, (float*)d_out);
}